// Round 1
// baseline (136.138 us; speedup 1.0000x reference)
//
#include <hip/hip_runtime.h>

// Problem constants (N = 4096 bodies, 2D).
#define NB 4096
#define KBROAD (4 * NB)   // 16384 broad-phase slots
#define KEXACT NB         // 4096 exact-phase slots

// ---------------------------------------------------------------------------
// Kernel 1: per-row broad-phase hit counts. One wave (64 lanes) per row i.
// Also initializes bi[] = -1 (first KBROAD global threads).
// ---------------------------------------------------------------------------
__global__ __launch_bounds__(256) void count_kernel(
    const float2* __restrict__ pos, const float* __restrict__ rad,
    int* __restrict__ row_counts, int* __restrict__ bi) {
  int gid = blockIdx.x * blockDim.x + threadIdx.x;
  if (gid < KBROAD) bi[gid] = -1;   // init before fill pass (separate dispatch)
  int i = gid >> 6;
  int lane = gid & 63;
  if (i >= NB) return;
  float2 pi = pos[i];
  float ri = rad[i];
  int cnt = 0;
  for (int j0 = 0; j0 < NB; j0 += 64) {
    int j = j0 + lane;
    float2 pj = pos[j];
    float rs = ri + rad[j];
    bool hit = (j != i) && (fabsf(pi.x - pj.x) <= rs) && (fabsf(pi.y - pj.y) <= rs);
    unsigned long long m = __ballot(hit);
    cnt += __popcll(m);   // uniform across lanes
  }
  if (lane == 0) row_counts[i] = cnt;
}

// ---------------------------------------------------------------------------
// Kernel 2: exclusive prefix sum over NB row counts. Single block, 1024 thr.
// ---------------------------------------------------------------------------
__global__ __launch_bounds__(1024) void scan_kernel(
    const int* __restrict__ row_counts, int* __restrict__ row_base) {
  __shared__ int part[1024];
  int t = threadIdx.x;
  int c0 = row_counts[t * 4 + 0];
  int c1 = row_counts[t * 4 + 1];
  int c2 = row_counts[t * 4 + 2];
  int c3 = row_counts[t * 4 + 3];
  int s = c0 + c1 + c2 + c3;
  part[t] = s;
  __syncthreads();
  // Hillis-Steele inclusive scan over 1024 partials.
  for (int off = 1; off < 1024; off <<= 1) {
    int v = (t >= off) ? part[t - off] : 0;
    __syncthreads();
    part[t] += v;
    __syncthreads();
  }
  int base = part[t] - s;   // exclusive
  row_base[t * 4 + 0] = base;
  row_base[t * 4 + 1] = base + c0;
  row_base[t * 4 + 2] = base + c0 + c1;
  row_base[t * 4 + 3] = base + c0 + c1 + c2;
}

// ---------------------------------------------------------------------------
// Kernel 3: fill broad pairs at their row-major global ranks. One wave/row.
// ---------------------------------------------------------------------------
__global__ __launch_bounds__(256) void fill_kernel(
    const float2* __restrict__ pos, const float* __restrict__ rad,
    const int* __restrict__ row_base, int* __restrict__ bi,
    int* __restrict__ bj) {
  int gid = blockIdx.x * blockDim.x + threadIdx.x;
  int i = gid >> 6;
  int lane = gid & 63;
  if (i >= NB) return;
  int rank = row_base[i];        // uniform across the wave
  if (rank >= KBROAD) return;    // whole row already past the cap
  float2 pi = pos[i];
  float ri = rad[i];
  for (int j0 = 0; j0 < NB; j0 += 64) {
    int j = j0 + lane;
    float2 pj = pos[j];
    float rs = ri + rad[j];
    bool hit = (j != i) && (fabsf(pi.x - pj.x) <= rs) && (fabsf(pi.y - pj.y) <= rs);
    unsigned long long m = __ballot(hit);
    int r = rank + __popcll(m & ((1ull << lane) - 1ull));
    if (hit && r < KBROAD) { bi[r] = i; bj[r] = j; }
    rank += __popcll(m);         // still uniform
    if (rank >= KBROAD) return;  // all later ranks >= cap
  }
}

// ---------------------------------------------------------------------------
// Kernel 4: exact phase + resolve, fused in ONE 1024-thread block.
// Each thread owns 16 contiguous broad slots (order-preserving), block scan
// assigns exact ranks; ev + last-writer slots live in LDS; then per-body
// combine implements the two sequential last-write-wins scatters.
// ---------------------------------------------------------------------------
__global__ __launch_bounds__(1024) void exact_kernel(
    const float2* __restrict__ pos, const float* __restrict__ rad,
    const int* __restrict__ bi, const int* __restrict__ bj,
    float2* __restrict__ out) {
  __shared__ int last_i[NB];      // 16 KB: max exact slot where body is ei
  __shared__ int last_j[NB];      // 16 KB: max exact slot where body is ej
  __shared__ float2 ev[KEXACT];   // 32 KB: penetration vectors by exact slot
  __shared__ int part[1024];      // 4 KB: block scan
  int t = threadIdx.x;
  for (int b = t; b < NB; b += 1024) { last_i[b] = -1; last_j[b] = -1; }
  __syncthreads();

  // Phase 1: count true penetrations among my 16 slots (explicit rn ops to
  // bit-match the numpy reference: sum(dx^2+dy^2)+1e-12, sqrt, radd-dist).
  int hitmask = 0;
  int cnt = 0;
  for (int k = 0; k < 16; ++k) {
    int s = t * 16 + k;
    int a = bi[s];
    if (a >= 0) {
      int b = bj[s];
      float2 pa = pos[a], pb = pos[b];
      float dx = pa.x - pb.x, dy = pa.y - pb.y;
      float ss = __fadd_rn(__fadd_rn(__fmul_rn(dx, dx), __fmul_rn(dy, dy)), 1e-12f);
      float dist = __fsqrt_rn(ss);
      float pen = __fsub_rn(__fadd_rn(rad[a], rad[b]), dist);
      if (pen > 0.0f) { hitmask |= (1 << k); ++cnt; }
    }
  }
  part[t] = cnt;
  __syncthreads();
  for (int off = 1; off < 1024; off <<= 1) {
    int v = (t >= off) ? part[t - off] : 0;
    __syncthreads();
    part[t] += v;
    __syncthreads();
  }
  int rank = part[t] - cnt;   // exclusive base for my first hit

  // Phase 2: recompute pen_vec for my hits, store at exact rank, record
  // last-writer slot per body (atomicMax over slot index, LDS scope).
  for (int k = 0; k < 16 && rank < KEXACT; ++k) {
    if (hitmask & (1 << k)) {
      int s = t * 16 + k;
      int a = bi[s], b = bj[s];
      float2 pa = pos[a], pb = pos[b];
      float dx = pa.x - pb.x, dy = pa.y - pb.y;
      float ss = __fadd_rn(__fadd_rn(__fmul_rn(dx, dx), __fmul_rn(dy, dy)), 1e-12f);
      float dist = __fsqrt_rn(ss);
      float pen = __fsub_rn(__fadd_rn(rad[a], rad[b]), dist);
      float sc = __fdiv_rn(pen, dist);
      ev[rank] = make_float2(__fmul_rn(dx, sc), __fmul_rn(dy, sc));
      atomicMax(&last_i[a], rank);
      atomicMax(&last_j[b], rank);
      ++rank;
    }
  }
  __syncthreads();

  // Phase 3: combine. j-scatter is applied after i-scatter, so it wins when
  // both touched a body; both use ORIGINAL pos (new_i/new_j read pos[]).
  for (int b = t; b < NB; b += 1024) {
    float2 p = pos[b];
    int lj = last_j[b];
    int li = last_i[b];
    float2 o = p;
    if (lj >= 0) {
      o.x = __fsub_rn(p.x, __fmul_rn(0.5f, ev[lj].x));
      o.y = __fsub_rn(p.y, __fmul_rn(0.5f, ev[lj].y));
    } else if (li >= 0) {
      o.x = __fadd_rn(p.x, __fmul_rn(0.5f, ev[li].x));
      o.y = __fadd_rn(p.y, __fmul_rn(0.5f, ev[li].y));
    }
    out[b] = o;
  }
}

// ---------------------------------------------------------------------------
extern "C" void kernel_launch(void* const* d_in, const int* in_sizes, int n_in,
                              void* d_out, int out_size, void* d_ws, size_t ws_size,
                              hipStream_t stream) {
  const float2* pos = (const float2*)d_in[0];   // [N,2] f32
  const float* rad = (const float*)d_in[1];     // [N]   f32
  float2* out = (float2*)d_out;                 // [N,2] f32

  // Workspace layout (all int32 unless noted):
  int* row_counts = (int*)d_ws;          // NB
  int* row_base   = row_counts + NB;     // NB
  int* bi         = row_base + NB;       // KBROAD
  int* bj         = bi + KBROAD;         // KBROAD
  // total: 160 KB << ws_size

  // 1 wave per row: NB*64 threads.
  dim3 rowGrid((NB * 64) / 256), rowBlk(256);
  count_kernel<<<rowGrid, rowBlk, 0, stream>>>(pos, rad, row_counts, bi);
  scan_kernel<<<1, 1024, 0, stream>>>(row_counts, row_base);
  fill_kernel<<<rowGrid, rowBlk, 0, stream>>>(pos, rad, row_base, bi, bj);
  exact_kernel<<<1, 1024, 0, stream>>>(pos, rad, bi, bj, out);
}

// Round 2
// 127.686 us; speedup vs baseline: 1.0662x; 1.0662x over previous
//
#include <hip/hip_runtime.h>

// N = 4096 bodies, 2D. Broad phase keeps first 4N row-major AABB hits,
// exact phase keeps first N true penetrations, resolve is last-write-wins.
#define NB 4096
#define KBROAD (4 * NB)   // 16384
#define KEXACT NB         // 4096
typedef unsigned long long u64;

// ---------------------------------------------------------------------------
// K1: broad-phase counts + per-row hit bitmasks. 2 rows per wave.
// Also zero-inits hitbits and last_i/last_j (ws is 0xAA-poisoned).
// Grid: 512 blocks x 256 threads = 2048 waves.
// ---------------------------------------------------------------------------
__global__ __launch_bounds__(256) void count_kernel(
    const float2* __restrict__ pos, const float* __restrict__ rad,
    int* __restrict__ row_counts, u64* __restrict__ masks,
    unsigned* __restrict__ hitbits, int* __restrict__ last_i,
    int* __restrict__ last_j) {
  int gid = blockIdx.x * blockDim.x + threadIdx.x;
  if (gid < 512) hitbits[gid] = 0;
  if (gid < NB) { last_i[gid] = -1; last_j[gid] = -1; }
  int wave = gid >> 6;
  int lane = gid & 63;
  int r0 = wave * 2;          // rows r0, r0+1
  float2 p0 = pos[r0], p1 = pos[r0 + 1];
  float ra0 = rad[r0], ra1 = rad[r0 + 1];
  u64 mw0 = 0, mw1 = 0;       // lane c keeps the mask word of chunk c
  int c0 = 0, c1 = 0;
  for (int c = 0; c < 64; ++c) {
    int j = c * 64 + lane;
    float2 pj = pos[j];
    float rj = rad[j];
    float rs0 = ra0 + rj, rs1 = ra1 + rj;
    bool h0 = (j != r0) && (fabsf(p0.x - pj.x) <= rs0) && (fabsf(p0.y - pj.y) <= rs0);
    bool h1 = (j != r0 + 1) && (fabsf(p1.x - pj.x) <= rs1) && (fabsf(p1.y - pj.y) <= rs1);
    u64 m0 = __ballot(h0);
    u64 m1 = __ballot(h1);
    if (lane == c) { mw0 = m0; mw1 = m1; }
    c0 += __popcll(m0);
    c1 += __popcll(m1);
  }
  masks[(size_t)r0 * 64 + lane] = mw0;          // coalesced 512 B per row
  masks[(size_t)(r0 + 1) * 64 + lane] = mw1;
  if (lane == 0) { row_counts[r0] = c0; row_counts[r0 + 1] = c1; }
}

// ---------------------------------------------------------------------------
// K2: per-block redundant full scan of row counts, then fill this block's 16
// rows from the stored masks AND run the exact circle test inline, writing
// bi/bj, penvec[slot], and a 16384-bit exact-hit bitmask (atomicOr).
// Grid: 256 blocks x 256 threads (wave w owns rows blk*16 + w*4 .. +3).
// ---------------------------------------------------------------------------
__global__ __launch_bounds__(256) void fill_kernel(
    const float2* __restrict__ pos, const float* __restrict__ rad,
    const int* __restrict__ row_counts, const u64* __restrict__ masks,
    int* __restrict__ bi, int* __restrict__ bj,
    float2* __restrict__ penvec, unsigned* __restrict__ hitbits) {
  __shared__ int rb[NB];     // exclusive base per row (16 KB)
  __shared__ int wsum[4];
  int t = threadIdx.x;
  int wv = t >> 6, lane = t & 63;
  // ---- stage 1: exclusive scan of 4096 counts (redundant per block).
  int c[16], s = 0;
  #pragma unroll
  for (int k = 0; k < 16; ++k) { c[k] = row_counts[t * 16 + k]; s += c[k]; }
  int v = s;  // wave inclusive scan
  #pragma unroll
  for (int off = 1; off < 64; off <<= 1) {
    int u = __shfl_up(v, off);
    if (lane >= off) v += u;
  }
  if (lane == 63) wsum[wv] = v;
  __syncthreads();
  int wbase = 0;
  #pragma unroll
  for (int w = 0; w < 4; ++w) if (w < wv) wbase += wsum[w];
  int run = wbase + v - s;   // exclusive base of thread t's first row
  #pragma unroll
  for (int k = 0; k < 16; ++k) { rb[t * 16 + k] = run; run += c[k]; }
  __syncthreads();
  // ---- stage 2: fill 4 rows per wave.
  for (int q = 0; q < 4; ++q) {
    int r = blockIdx.x * 16 + wv * 4 + q;
    int rank = rb[r];                       // uniform across wave
    if (rank >= KBROAD) continue;
    float2 pr = pos[r];
    float rr = rad[r];
    u64 myw = masks[(size_t)r * 64 + lane]; // lane c holds chunk c's word
    for (int ch = 0; ch < 64; ++ch) {
      u64 m = __shfl(myw, ch);              // uniform
      if (m) {
        bool b = (m >> lane) & 1ull;
        int rl = rank + __popcll(m & ((1ull << lane) - 1ull));
        if (b && rl < KBROAD) {
          int j = ch * 64 + lane;
          bi[rl] = r;
          bj[rl] = j;
          // exact circle test, rn ops to bit-match numpy (no FMA contraction)
          float2 pj = pos[j];
          float dx = pr.x - pj.x, dy = pr.y - pj.y;
          float ss = __fadd_rn(__fadd_rn(__fmul_rn(dx, dx), __fmul_rn(dy, dy)), 1e-12f);
          float dist = __fsqrt_rn(ss);
          float pen = __fsub_rn(__fadd_rn(rr, rad[j]), dist);
          if (pen > 0.0f) {
            float sc = __fdiv_rn(pen, dist);
            penvec[rl] = make_float2(__fmul_rn(dx, sc), __fmul_rn(dy, sc));
            atomicOr(&hitbits[rl >> 5], 1u << (rl & 31));
          }
        }
        rank += __popcll(m);                // still uniform
      }
      if (rank >= KBROAD) break;
    }
  }
}

// ---------------------------------------------------------------------------
// K3: exact compaction. Each block redundantly popcount-scans the 512-word
// hit bitmask (2 block barriers), then its 256 threads place candidates
// s = blk*256 + t: ev[rank] = penvec[s]; last-writer via atomicMax.
// Grid: 64 blocks x 256 threads.
// ---------------------------------------------------------------------------
__global__ __launch_bounds__(256) void exact_kernel(
    const unsigned* __restrict__ hitbits, const int* __restrict__ bi,
    const int* __restrict__ bj, const float2* __restrict__ penvec,
    float2* __restrict__ ev, int* __restrict__ last_i,
    int* __restrict__ last_j) {
  __shared__ unsigned hb[512];
  __shared__ int wb[512];
  __shared__ int wsum[4];
  int t = threadIdx.x;
  int wv = t >> 6, lane = t & 63;
  unsigned w0 = hitbits[2 * t], w1 = hitbits[2 * t + 1];
  hb[2 * t] = w0;
  hb[2 * t + 1] = w1;
  int cnt = __popc(w0) + __popc(w1);
  int v = cnt;
  #pragma unroll
  for (int off = 1; off < 64; off <<= 1) {
    int u = __shfl_up(v, off);
    if (lane >= off) v += u;
  }
  if (lane == 63) wsum[wv] = v;
  __syncthreads();
  int wbase = 0;
  #pragma unroll
  for (int w = 0; w < 4; ++w) if (w < wv) wbase += wsum[w];
  int excl = wbase + v - cnt;
  wb[2 * t] = excl;
  wb[2 * t + 1] = excl + __popc(w0);
  __syncthreads();
  int s = blockIdx.x * 256 + t;
  unsigned word = hb[s >> 5];
  if ((word >> (s & 31)) & 1u) {
    int rank = wb[s >> 5] + __popc(word & ((1u << (s & 31)) - 1u));
    if (rank < KEXACT) {
      ev[rank] = penvec[s];
      atomicMax(&last_i[bi[s]], rank);
      atomicMax(&last_j[bj[s]], rank);
    }
  }
}

// ---------------------------------------------------------------------------
// K4: resolve. j-scatter wins over i-scatter; both read ORIGINAL pos.
// Grid: 16 blocks x 256 threads.
// ---------------------------------------------------------------------------
__global__ __launch_bounds__(256) void combine_kernel(
    const float2* __restrict__ pos, const int* __restrict__ last_i,
    const int* __restrict__ last_j, const float2* __restrict__ ev,
    float2* __restrict__ out) {
  int b = blockIdx.x * blockDim.x + threadIdx.x;
  float2 p = pos[b];
  int lj = last_j[b], li = last_i[b];
  float2 o = p;
  if (lj >= 0) {
    o.x = __fsub_rn(p.x, __fmul_rn(0.5f, ev[lj].x));
    o.y = __fsub_rn(p.y, __fmul_rn(0.5f, ev[lj].y));
  } else if (li >= 0) {
    o.x = __fadd_rn(p.x, __fmul_rn(0.5f, ev[li].x));
    o.y = __fadd_rn(p.y, __fmul_rn(0.5f, ev[li].y));
  }
  out[b] = o;
}

// ---------------------------------------------------------------------------
extern "C" void kernel_launch(void* const* d_in, const int* in_sizes, int n_in,
                              void* d_out, int out_size, void* d_ws, size_t ws_size,
                              hipStream_t stream) {
  const float2* pos = (const float2*)d_in[0];
  const float* rad = (const float*)d_in[1];
  float2* out = (float2*)d_out;

  // Workspace layout (~2.5 MB of the 256 MB ws).
  u64* masks = (u64*)d_ws;                       // NB*64 u64 = 2 MB
  float2* penvec = (float2*)(masks + (size_t)NB * 64);  // KBROAD float2
  float2* ev = penvec + KBROAD;                  // KEXACT float2
  int* row_counts = (int*)(ev + KEXACT);         // NB
  int* bi = row_counts + NB;                     // KBROAD
  int* bj = bi + KBROAD;                         // KBROAD
  unsigned* hitbits = (unsigned*)(bj + KBROAD);  // 512
  int* last_i = (int*)(hitbits + 512);           // NB
  int* last_j = last_i + NB;                     // NB

  count_kernel<<<512, 256, 0, stream>>>(pos, rad, row_counts, masks, hitbits,
                                        last_i, last_j);
  fill_kernel<<<256, 256, 0, stream>>>(pos, rad, row_counts, masks, bi, bj,
                                       penvec, hitbits);
  exact_kernel<<<64, 256, 0, stream>>>(hitbits, bi, bj, penvec, ev, last_i,
                                       last_j);
  combine_kernel<<<16, 256, 0, stream>>>(pos, last_i, last_j, ev, out);
}